// Round 1
// baseline (184.792 us; speedup 1.0000x reference)
//
#include <hip/hip_runtime.h>

#define T_DIM 2048
#define F_DIM 16
#define B_DIM 1024
#define STEPS 300

// K1: per-batch constants c_j(b) = td_j * 10, plus zero-init of valid[].
__global__ void k1_prep(const float* __restrict__ x, const float* __restrict__ wptr,
                        float* __restrict__ cbuf, unsigned* __restrict__ valid) {
#pragma clang fp contract(off)
    int b = blockIdx.x * blockDim.x + threadIdx.x;
    if (b < STEPS) valid[b] = 0u;   // harness poisons ws with 0xAA every call
    if (b >= B_DIM) return;
    const float* xl = x + ((size_t)b * T_DIM + (T_DIM - 1)) * F_DIM;  // x_last row
    float w = *wptr;
    float d = 0.0f;
#pragma unroll
    for (int j0 = 0; j0 < 4; ++j0) {           // j = j0+1
        d = d + xl[j0];                         // sequential prefix sum, matches np.sum
        float den = w + xl[5 + j0] * 25.0f;     // x_last[:, 4+j]
        float td  = (d * 150.0f) / den;         // exact op order, IEEE div
        cbuf[j0 * B_DIM + b] = td * 10.0f;
    }
}

// K2: valid[i] bitmask over j — OR over all batches of (gathered value != 0).
__global__ void k2_valid(const float* __restrict__ x, const float* __restrict__ cbuf,
                         unsigned* __restrict__ valid) {
#pragma clang fp contract(off)
    int i = blockIdx.x;                               // forward step
    int b = blockIdx.y * blockDim.x + threadIdx.x;    // batch
    unsigned m = 0;
#pragma unroll
    for (int j0 = 0; j0 < 4; ++j0) {
        float c = cbuf[j0 * B_DIM + b];
        int idx = (int)((float)i - c);                // trunc-toward-zero == astype(int32)
        idx = idx < 0 ? 0 : (idx > T_DIM - 1 ? T_DIM - 1 : idx);
        float v = x[((size_t)b * T_DIM + idx) * F_DIM + 10 + j0];  // feature 9+j
        if (v != 0.0f) m |= 1u << j0;
    }
    unsigned wm = 0;
#pragma unroll
    for (int j0 = 0; j0 < 4; ++j0) {
        if (__ballot((m >> j0) & 1u) != 0ull) wm |= 1u << j0;
    }
    if ((threadIdx.x & 63) == 0 && wm) atomicOr(&valid[i], wm);
}

// K3: select first valid j per step, gather, write out[b*300 + i].
__global__ void k3_out(const float* __restrict__ x, const float* __restrict__ cbuf,
                       const unsigned* __restrict__ valid, float* __restrict__ out) {
#pragma clang fp contract(off)
    int g = blockIdx.x * blockDim.x + threadIdx.x;
    if (g >= B_DIM * STEPS) return;
    int b = g / STEPS;
    int i = g - b * STEPS;
    unsigned m = valid[i];
    float r = 0.0f;
    if (m) {
        int j0 = __ffs(m) - 1;                        // argmax of bool == first True
        float c = cbuf[j0 * B_DIM + b];
        int idx = (int)((float)i - c);
        idx = idx < 0 ? 0 : (idx > T_DIM - 1 ? T_DIM - 1 : idx);
        r = x[((size_t)b * T_DIM + idx) * F_DIM + 10 + j0];
    }
    out[g] = r;
}

extern "C" void kernel_launch(void* const* d_in, const int* in_sizes, int n_in,
                              void* d_out, int out_size, void* d_ws, size_t ws_size,
                              hipStream_t stream) {
    const float* x    = (const float*)d_in[3];   // x_input (B,T,F)
    const float* wptr = (const float*)d_in[4];   // scalar w
    float* out = (float*)d_out;                  // (B, 300) row-major

    float*    cbuf  = (float*)d_ws;                                   // 4*1024 f32
    unsigned* valid = (unsigned*)((char*)d_ws + 4 * B_DIM * sizeof(float)); // 300 u32

    hipLaunchKernelGGL(k1_prep, dim3(4), dim3(256), 0, stream, x, wptr, cbuf, valid);
    hipLaunchKernelGGL(k2_valid, dim3(STEPS, 4), dim3(256), 0, stream, x, cbuf, valid);
    hipLaunchKernelGGL(k3_out, dim3((B_DIM * STEPS + 255) / 256), dim3(256), 0, stream,
                       x, cbuf, valid, out);
}